// Round 1
// 1184.889 us; speedup vs baseline: 1.8659x; 1.8659x over previous
//
#include <hip/hip_runtime.h>
#include <stdint.h>

typedef unsigned short u16;
typedef unsigned int u32;

#define L_STEPS 64
#define B_SZ 32
#define H_SZ 256
#define Z_SZ 256
#define V_SZ 32000
#define H2 128          // H/2 (f16 pairs per row)
#define G3H 768         // 3*H

typedef _Float16 h2_t __attribute__((ext_vector_type(2)));

// ---- workspace layout in h2_t units (4 bytes each) ----
// All weight mats now stored WAVE-TILED:
//   off(row,k2) = (((row>>6)*32 + (k2>>2))*64 + (row&63))*4 + (k2&3)
// so at each k2-quad a wave's 64 lanes load one coalesced dwordx4 (1KB).
#define WHH2_OFF   0            // 4 mats x 98304 (enc_c, enc_s, dec_c, dec_s)
#define WIH2_OFF   393216       // 4 mats x 98304
#define WM2_OFF    786432       // 32768
#define WLV2_OFF   819200       // 32768
#define WL2H2_OFF  851968       // 32768
#define GI2_OFF    884736       // f16 gi: 4*2048*384 = 3,145,728 h2
#define OUTS2_OFF  4030464      // 2048*128 = 262,144 h2
// total 4,292,608 h2 = 17.2 MB

// ---- d_out layout (fp32 elements) ----
#define OUT_MEAN_OFF  65536000
#define OUT_LOGV_OFF  65544192
#define OUT_Z_OFF     65552384

__device__ __forceinline__ float fdot2(h2_t a, h2_t b, float c){
#if __has_builtin(__builtin_amdgcn_fdot2)
  return __builtin_amdgcn_fdot2(a, b, c, false);
#else
  return c + (float)a.x*(float)b.x + (float)a.y*(float)b.y;
#endif
}
__device__ __forceinline__ float sigm(float x){ return 1.f/(1.f + __expf(-x)); }

// ============ pack fp32 weight mats -> f16x2 wave-tiled ============
struct PackTArgs { const float2* src[11]; int n_h2[11]; int dstoff[11]; };

__global__ __launch_bounds__(256) void k_packt(PackTArgs p, h2_t* wsh){
  int m = blockIdx.y;
  int r = blockIdx.x*256 + threadIdx.x;       // linear over [rows][128] h2 pairs
  if (r >= p.n_h2[m]) return;
  int row = r >> 7, k2 = r & 127;
  float2 f = p.src[m][r];
  h2_t h; h.x = (_Float16)f.x; h.y = (_Float16)f.y;
  int off = (((row>>6)*32 + (k2>>2))*64 + (row&63))*4 + (k2&3);
  wsh[p.dstoff[m] + off] = h;
}

// ============ gi[g][l][b][768] = emb[nodes[l,b]] @ Wih_g^T + bih_g  (stored f16) ============
struct GiArgs { const float* bih[4]; };

__global__ __launch_bounds__(256) void k_gi(const int* __restrict__ nodes,
                                            const float* __restrict__ emb,
                                            const h2_t* __restrict__ wih2,
                                            GiArgs ga, h2_t* __restrict__ gi2){
  int l = blockIdx.x, g = blockIdx.y, t = threadIdx.x;
  __shared__ __align__(16) h2_t x2[B_SZ*132];   // [b][k2], stride 132 (pad)
  #pragma unroll
  for (int it=0; it<16; ++it){
    int lin = it*256 + t;
    int bb = lin >> 7, k2 = lin & 127;
    int node = nodes[l*B_SZ + bb];
    float2 f = ((const float2*)(emb + (size_t)node*H_SZ))[k2];
    h2_t r; r.x=(_Float16)f.x; r.y=(_Float16)f.y;
    x2[bb*132 + k2] = r;
  }
  __syncthreads();
  const float* bih = ga.bih[g];
  for (int jc=0; jc<3; ++jc){
    int j = jc*256 + t;                 // this thread computes gate-row j for all 32 b
    float acc[32];
    #pragma unroll
    for (int bb=0;bb<32;bb++) acc[bb]=0.f;
    // wave-tiled W: coalesced dwordx4 per wave per k2-quad
    const float4* Wv = (const float4*)wih2 + (size_t)g*24576 + (j>>6)*2048 + (j&63);
    #pragma unroll 2
    for (int kb=0;kb<32;kb++){
      union{float4 f; h2_t h[4];} w4;
      w4.f = Wv[kb*64];
      #pragma unroll
      for (int kc=0;kc<4;kc++){
        h2_t w = w4.h[kc];
        int k2 = kb*4 + kc;
        #pragma unroll
        for (int bb=0;bb<32;bb++) acc[bb] = fdot2(x2[bb*132+k2], w, acc[bb]);
      }
    }
    float bvv = bih[j];
    int base = (g*2048 + l*B_SZ)*384 + (j>>1);
    #pragma unroll
    for (int bb=0;bb<32;bb++){
      float own = acc[bb] + bvv;
      float oth = __shfl_xor(own, 1, 64);   // pair rows (2m, 2m+1)
      if (!(t&1)){
        h2_t r; r.x=(_Float16)own; r.y=(_Float16)oth;
        gi2[base + bb*384] = r;
      }
    }
  }
}

// ============ sequential scan: encoder -> latent -> decoder. one block per b ============
struct ScanArgs {
  const float* bhh[4];
  const float* b_mean; const float* b_logv; const float* b_l2h;
  const float* enc_init; const float* eps;
};

__global__ __launch_bounds__(768) void k_scan(const int* __restrict__ edges, ScanArgs sa,
                                              const h2_t* __restrict__ wsh,
                                              h2_t* __restrict__ outs2,
                                              float* __restrict__ out){
  int b = blockIdx.x, t = threadIdx.x;
  int i = t & 255, gate = t >> 8;       // thread owns Whh row t of the selected GRU
  int lane = t & 63, rb = t >> 6;
  __shared__ float h_lds[H_SZ];
  __shared__ __align__(16) h2_t hs2[H2];
  __shared__ float g_lds[512];          // z,n pre-activations from threads 256..767
  __shared__ float s_bhh[4*G3H];        // 12 KB: all 4 bhh vectors
  __shared__ int s_edge[L_STEPS];
  const _Float16* gi_all = (const _Float16*)(wsh + GI2_OFF);

  if (t < H_SZ) h_lds[t] = sa.enc_init[b*H_SZ + t];
  if (t < L_STEPS) s_edge[t] = edges[t*B_SZ + b];
  #pragma unroll
  for (int m=0;m<4;m++) s_bhh[m*G3H + t] = sa.bhh[m][t];
  __syncthreads();
  if (t < H2){ h2_t r; r.x=(_Float16)h_lds[2*t]; r.y=(_Float16)h_lds[2*t+1]; hs2[t]=r; }
  __syncthreads();

  const float4* hsv = (const float4*)hs2;

  for (int ph=0; ph<2; ++ph){
    for (int l=0; l<L_STEPS; ++l){
      int e = s_edge[l];
      int gsel = (ph ? 2 : 0) + (e ? 0 : 1);   // edge!=0 -> child params
      // prefetch input-side gates + bias (independent of this step's dots)
      float gi0=0.f, gi1=0.f, gi2v=0.f;
      if (t < H_SZ){
        const _Float16* gr = gi_all + (size_t)(gsel*2048 + l*B_SZ + b)*G3H;
        gi0  = (float)gr[i];
        gi1  = (float)gr[256+i];
        gi2v = (float)gr[512+i];
      }
      float bv = s_bhh[gsel*G3H + t];
      // wave-tiled Whh: one coalesced dwordx4 per wave per k2-quad
      const float4* Wv = (const float4*)wsh + (size_t)gsel*24576 + rb*2048 + lane;
      float a0=0.f,a1=0.f,a2=0.f,a3=0.f;
      #pragma unroll 8
      for (int kb=0;kb<32;kb++){
        union{float4 f; h2_t h[4];} w, x;
        w.f = Wv[kb*64];
        x.f = hsv[kb];                  // LDS broadcast
        a0 = fdot2(x.h[0], w.h[0], a0);
        a1 = fdot2(x.h[1], w.h[1], a1);
        a2 = fdot2(x.h[2], w.h[2], a2);
        a3 = fdot2(x.h[3], w.h[3], a3);
      }
      float acc = (a0+a1)+(a2+a3) + bv;
      if (gate) g_lds[(gate-1)*256 + i] = acc;
      __syncthreads();                  // g_lds ready; all hs2 reads of this step done
      if (t < H_SZ){
        float r = sigm(gi0 + acc);                 // ir+hr (own dot = r-row)
        float z = sigm(gi1 + g_lds[i]);            // iz+hz
        float n = tanhf(gi2v + r*g_lds[256+i]);    // inn + r*(hn+bhh_n)
        float hn = (1.f - z)*n + z*h_lds[i];
        h_lds[i] = hn;
        float ho = __shfl_xor(hn, 1, 64);          // pair (2m,2m+1)
        if (!(i & 1)){
          h2_t pk; pk.x=(_Float16)hn; pk.y=(_Float16)ho;
          hs2[i>>1] = pk;
          if (ph) outs2[(l*B_SZ + b)*H2 + (i>>1)] = pk;
        }
      }
      __syncthreads();                  // hs2 ready for next step
    }

    if (ph == 0){
      // latent: mean/logv/z/h0 — per-b local
      if (t < H_SZ){
        const float4* WmV = (const float4*)(wsh + WM2_OFF)  + (t>>6)*2048 + (t&63);
        const float4* WlV = (const float4*)(wsh + WLV2_OFF) + (t>>6)*2048 + (t&63);
        float m0=0.f,m1=0.f,m2=0.f,m3=0.f, l0=0.f,l1=0.f,l2=0.f,l3=0.f;
        #pragma unroll 8
        for (int kb=0;kb<32;kb++){
          union{float4 f; h2_t h[4];} wm, wl, x;
          x.f  = hsv[kb];
          wm.f = WmV[kb*64];
          wl.f = WlV[kb*64];
          m0=fdot2(x.h[0],wm.h[0],m0); m1=fdot2(x.h[1],wm.h[1],m1);
          m2=fdot2(x.h[2],wm.h[2],m2); m3=fdot2(x.h[3],wm.h[3],m3);
          l0=fdot2(x.h[0],wl.h[0],l0); l1=fdot2(x.h[1],wl.h[1],l1);
          l2=fdot2(x.h[2],wl.h[2],l2); l3=fdot2(x.h[3],wl.h[3],l3);
        }
        float am = (m0+m1)+(m2+m3) + sa.b_mean[t];
        float al = (l0+l1)+(l2+l3) + sa.b_logv[t];
        float zv = sa.eps[b*Z_SZ + t] * __expf(0.5f*al) + am;
        out[OUT_MEAN_OFF + b*Z_SZ + t] = am;
        out[OUT_LOGV_OFF + b*Z_SZ + t] = al;
        out[OUT_Z_OFF    + b*Z_SZ + t] = zv;
        h_lds[t] = zv;
      }
      __syncthreads();
      if (t < H2){ h2_t r; r.x=(_Float16)h_lds[2*t]; r.y=(_Float16)h_lds[2*t+1]; hs2[t]=r; }
      __syncthreads();
      float h0v = 0.f;
      if (t < H_SZ){
        const float4* WzV = (const float4*)(wsh + WL2H2_OFF) + (t>>6)*2048 + (t&63);
        float z0=0.f,z1=0.f,z2=0.f,z3=0.f;
        #pragma unroll 8
        for (int kb=0;kb<32;kb++){
          union{float4 f; h2_t h[4];} w, x;
          x.f = hsv[kb];
          w.f = WzV[kb*64];
          z0=fdot2(x.h[0],w.h[0],z0); z1=fdot2(x.h[1],w.h[1],z1);
          z2=fdot2(x.h[2],w.h[2],z2); z3=fdot2(x.h[3],w.h[3],z3);
        }
        h0v = (z0+z1)+(z2+z3) + sa.b_l2h[t];
      }
      __syncthreads();                  // all hs2 reads of h0-dot done
      if (t < H_SZ) h_lds[t] = h0v;
      __syncthreads();
      if (t < H2){ h2_t r; r.x=(_Float16)h_lds[2*t]; r.y=(_Float16)h_lds[2*t+1]; hs2[t]=r; }
      __syncthreads();
    }
  }
}

// ============ logits = outs @ W_voc^T + b_voc  (fp32 out into d_out) ============
// M=2048 (128/blk), N=32000 (256/blk), K2=128. fdot2 register tile 8x8. W_voc converted fp32->f16 in staging.
__global__ __launch_bounds__(512) void k_gemm(const h2_t* __restrict__ outs2,
                                              const float* __restrict__ wv,
                                              const float* __restrict__ bvoc,
                                              float* __restrict__ outf){
  int t = threadIdx.x;
  int vq = t & 31, rq = t >> 5;          // rq 0..15
  int Nb = blockIdx.x * 256, Mb = blockIdx.y * 128;
  __shared__ __align__(16) h2_t A[16*128];    // [k2][r]
  __shared__ __align__(16) h2_t Bs[16*256];   // [k2][v]
  float acc[8][8];
  #pragma unroll
  for (int a=0;a<8;a++){
    #pragma unroll
    for (int c=0;c<8;c++) acc[a][c]=0.f;
  }

  for (int kc=0;kc<8;kc++){
    { // stage A: 128 r x 16 k2 from f16-packed outs2
      int r = t >> 2, q = t & 3;
      union{float4 f; h2_t h[4];} u;
      u.f = ((const float4*)(outs2 + (Mb + r)*H2 + kc*16))[q];
      #pragma unroll
      for (int uu=0; uu<4; ++uu) A[(q*4+uu)*128 + r] = u.h[uu];
    }
    { // stage B: 256 v x 16 k2, converting fp32 W_voc on the fly
      int v = t >> 1, q = t & 1;
      const float* wrow = wv + (size_t)(Nb + v)*H_SZ + kc*32 + q*16;
      #pragma unroll
      for (int p=0;p<4;p++){
        float4 f = ((const float4*)wrow)[p];
        h2_t h0; h0.x=(_Float16)f.x; h0.y=(_Float16)f.y;
        h2_t h1; h1.x=(_Float16)f.z; h1.y=(_Float16)f.w;
        Bs[(q*8+p*2  )*256 + v] = h0;
        Bs[(q*8+p*2+1)*256 + v] = h1;
      }
    }
    __syncthreads();
    #pragma unroll 2
    for (int k2=0;k2<16;k2++){
      union{float4 f; h2_t h[4];} a0, a1, b0, b1;
      a0.f = *(const float4*)(A  + k2*128 + rq*8);
      a1.f = *(const float4*)(A  + k2*128 + rq*8 + 4);
      b0.f = *(const float4*)(Bs + k2*256 + vq*4);
      b1.f = *(const float4*)(Bs + k2*256 + vq*4 + 128);
      #pragma unroll
      for (int ii=0;ii<8;ii++){
        h2_t av = (ii<4)? a0.h[ii] : a1.h[ii-4];
        #pragma unroll
        for (int jj=0;jj<8;jj++){
          h2_t bv = (jj<4)? b0.h[jj] : b1.h[jj-4];
          acc[ii][jj] = fdot2(av, bv, acc[ii][jj]);
        }
      }
    }
    __syncthreads();
  }

  float bias0[4], bias1[4];
  #pragma unroll
  for (int jj=0;jj<4;jj++){
    bias0[jj] = bvoc[Nb + 4*vq + jj];
    bias1[jj] = bvoc[Nb + 128 + 4*vq + jj];
  }
  #pragma unroll
  for (int ii=0;ii<8;ii++){
    size_t base = (size_t)(Mb + rq*8 + ii)*(size_t)V_SZ + (size_t)Nb;
    float4 o0, o1;
    o0.x = acc[ii][0]+bias0[0]; o0.y = acc[ii][1]+bias0[1];
    o0.z = acc[ii][2]+bias0[2]; o0.w = acc[ii][3]+bias0[3];
    o1.x = acc[ii][4]+bias1[0]; o1.y = acc[ii][5]+bias1[1];
    o1.z = acc[ii][6]+bias1[2]; o1.w = acc[ii][7]+bias1[3];
    *(float4*)(outf + base + 4*vq)       = o0;
    *(float4*)(outf + base + 128 + 4*vq) = o1;
  }
}

// ============ per-row log_softmax in-place over fp32 logits (register-resident row) ============
__global__ __launch_bounds__(256) void k_softmax(float* __restrict__ outf){
  int rrow = blockIdx.x, t = threadIdx.x;
  float4* row = (float4*)(outf + (size_t)rrow * V_SZ);   // 8000 float4
  float4 v[32];
  #pragma unroll
  for (int i=0;i<31;i++) v[i] = row[i*256 + t];
  if (t < 64) v[31] = row[7936 + t];
  else { v[31].x = -1e30f; v[31].y = -1e30f; v[31].z = -1e30f; v[31].w = -1e30f; }

  float m = -1e30f;
  #pragma unroll
  for (int i=0;i<32;i++) m = fmaxf(m, fmaxf(fmaxf(v[i].x, v[i].y), fmaxf(v[i].z, v[i].w)));

  __shared__ float sred[4];
  __shared__ float sbc;
  int wid = t >> 6, lane = t & 63;
  #pragma unroll
  for (int o=32;o;o>>=1) m = fmaxf(m, __shfl_xor(m, o, 64));
  if (lane==0) sred[wid] = m;
  __syncthreads();
  if (t==0) sbc = fmaxf(fmaxf(sred[0],sred[1]), fmaxf(sred[2],sred[3]));
  __syncthreads();
  m = sbc;
  __syncthreads();

  float s = 0.f;
  #pragma unroll
  for (int i=0;i<32;i++){
    s += __expf(v[i].x - m) + __expf(v[i].y - m) + __expf(v[i].z - m) + __expf(v[i].w - m);
  }
  #pragma unroll
  for (int o=32;o;o>>=1) s += __shfl_xor(s, o, 64);
  if (lane==0) sred[wid] = s;
  __syncthreads();
  if (t==0) sbc = sred[0]+sred[1]+sred[2]+sred[3];
  __syncthreads();
  float lse = m + logf(sbc);

  #pragma unroll
  for (int i=0;i<31;i++){
    v[i].x -= lse; v[i].y -= lse; v[i].z -= lse; v[i].w -= lse;
    row[i*256 + t] = v[i];
  }
  if (t < 64){
    v[31].x -= lse; v[31].y -= lse; v[31].z -= lse; v[31].w -= lse;
    row[7936 + t] = v[31];
  }
}

// ============================================================================
extern "C" void kernel_launch(void* const* d_in, const int* in_sizes, int n_in,
                              void* d_out, int out_size, void* d_ws, size_t ws_size,
                              hipStream_t stream){
  const int* nodes = (const int*)d_in[0];
  const int* edges = (const int*)d_in[1];
  h2_t* wsh = (h2_t*)d_ws;
  float* outf = (float*)d_out;

  // ---- pack all weights fp32 -> f16, wave-tiled ----
  PackTArgs pt;
  const int srcidx[11] = {6,10,14,18, 5,9,13,17, 21,23,25};
  for (int k=0;k<11;k++){
    pt.src[k] = (const float2*)d_in[srcidx[k]];
    pt.n_h2[k] = (k < 8) ? 98304 : 32768;
  }
  for (int k=0;k<4;k++) pt.dstoff[k]   = WHH2_OFF + k*98304;
  for (int k=0;k<4;k++) pt.dstoff[4+k] = WIH2_OFF + k*98304;
  pt.dstoff[8] = WM2_OFF; pt.dstoff[9] = WLV2_OFF; pt.dstoff[10] = WL2H2_OFF;
  k_packt<<<dim3(384,11), dim3(256), 0, stream>>>(pt, wsh);

  // ---- gi precompute (f16) ----
  GiArgs ga;
  ga.bih[0]=(const float*)d_in[7];  ga.bih[1]=(const float*)d_in[11];
  ga.bih[2]=(const float*)d_in[15]; ga.bih[3]=(const float*)d_in[19];
  k_gi<<<dim3(64,4), dim3(256), 0, stream>>>(nodes, (const float*)d_in[4], wsh + WIH2_OFF, ga, wsh + GI2_OFF);

  // ---- recurrent scan (enc -> latent -> dec), one block per b ----
  ScanArgs sa;
  sa.bhh[0]=(const float*)d_in[8];  sa.bhh[1]=(const float*)d_in[12];
  sa.bhh[2]=(const float*)d_in[16]; sa.bhh[3]=(const float*)d_in[20];
  sa.b_mean=(const float*)d_in[22]; sa.b_logv=(const float*)d_in[24]; sa.b_l2h=(const float*)d_in[26];
  sa.enc_init=(const float*)d_in[2]; sa.eps=(const float*)d_in[3];
  k_scan<<<dim3(32), dim3(768), 0, stream>>>(edges, sa, wsh, wsh + OUTS2_OFF, outf);

  // ---- vocab projection (fp32 logits into d_out) ----
  k_gemm<<<dim3(125,16), dim3(512), 0, stream>>>(wsh + OUTS2_OFF, (const float*)d_in[27], (const float*)d_in[28], outf);

  // ---- log_softmax in place ----
  k_softmax<<<dim3(2048), dim3(256), 0, stream>>>(outf);
}

// Round 2
// 971.152 us; speedup vs baseline: 2.2765x; 1.2201x over previous
//
#include <hip/hip_runtime.h>
#include <stdint.h>

typedef unsigned short u16;
typedef unsigned int u32;

#define L_STEPS 64
#define B_SZ 32
#define H_SZ 256
#define Z_SZ 256
#define V_SZ 32000
#define H2 128          // H/2 (f16 pairs per row)
#define G3H 768         // 3*H

typedef _Float16 h2_t __attribute__((ext_vector_type(2)));
typedef _Float16 f16x8 __attribute__((ext_vector_type(8)));
typedef float f32x4 __attribute__((ext_vector_type(4)));

// ---- workspace layout in h2_t units (4 bytes each) ----
// Recurrent/latent weight mats stored WAVE-TILED:
//   off(row,k2) = (((row>>6)*32 + (k2>>2))*64 + (row&63))*4 + (k2&3)
#define WHH2_OFF   0            // 4 mats x 98304 (enc_c, enc_s, dec_c, dec_s)
#define WIH2_OFF   393216       // 4 mats x 98304
#define WM2_OFF    786432       // 32768
#define WLV2_OFF   819200       // 32768
#define WL2H2_OFF  851968       // 32768
#define GI2_OFF    884736       // f16 gi: 4*2048*384 = 3,145,728 h2
#define OUTS2_OFF  4030464      // 2048*128 = 262,144 h2
#define W16_OFF    4292608      // W_voc f16 row-major: 32000*128 = 4,096,000 h2
#define WS_NEEDED  ((size_t)(W16_OFF + 4096000) * 4)   // 33,554,432 B = 32 MB

// ---- d_out layout (fp32 elements) ----
#define OUT_MEAN_OFF  65536000
#define OUT_LOGV_OFF  65544192
#define OUT_Z_OFF     65552384

__device__ __forceinline__ float fdot2(h2_t a, h2_t b, float c){
#if __has_builtin(__builtin_amdgcn_fdot2)
  return __builtin_amdgcn_fdot2(a, b, c, false);
#else
  return c + (float)a.x*(float)b.x + (float)a.y*(float)b.y;
#endif
}
__device__ __forceinline__ float sigm(float x){ return 1.f/(1.f + __expf(-x)); }

// ============ pack fp32 weight mats -> f16x2 wave-tiled ============
struct PackTArgs { const float2* src[11]; int n_h2[11]; int dstoff[11]; };

__global__ __launch_bounds__(256) void k_packt(PackTArgs p, h2_t* wsh){
  int m = blockIdx.y;
  int r = blockIdx.x*256 + threadIdx.x;       // linear over [rows][128] h2 pairs
  if (r >= p.n_h2[m]) return;
  int row = r >> 7, k2 = r & 127;
  float2 f = p.src[m][r];
  h2_t h; h.x = (_Float16)f.x; h.y = (_Float16)f.y;
  int off = (((row>>6)*32 + (k2>>2))*64 + (row&63))*4 + (k2&3);
  wsh[p.dstoff[m] + off] = h;
}

// ============ pack W_voc fp32 -> f16 row-major [V][256] ============
__global__ __launch_bounds__(256) void k_packv(const float2* __restrict__ src,
                                               h2_t* __restrict__ dst, int total){
  int idx = blockIdx.x*256 + threadIdx.x;
  if (idx >= total) return;
  float2 f = src[idx];
  h2_t h; h.x = (_Float16)f.x; h.y = (_Float16)f.y;
  dst[idx] = h;
}

// ============ gi[g][l][b][768] = emb[nodes[l,b]] @ Wih_g^T + bih_g  (stored f16) ============
struct GiArgs { const float* bih[4]; };

__global__ __launch_bounds__(256) void k_gi(const int* __restrict__ nodes,
                                            const float* __restrict__ emb,
                                            const h2_t* __restrict__ wih2,
                                            GiArgs ga, h2_t* __restrict__ gi2){
  int l = blockIdx.x, g = blockIdx.y, t = threadIdx.x;
  __shared__ __align__(16) h2_t x2[B_SZ*132];   // [b][k2], stride 132 (pad)
  #pragma unroll
  for (int it=0; it<16; ++it){
    int lin = it*256 + t;
    int bb = lin >> 7, k2 = lin & 127;
    int node = nodes[l*B_SZ + bb];
    float2 f = ((const float2*)(emb + (size_t)node*H_SZ))[k2];
    h2_t r; r.x=(_Float16)f.x; r.y=(_Float16)f.y;
    x2[bb*132 + k2] = r;
  }
  __syncthreads();
  const float* bih = ga.bih[g];
  for (int jc=0; jc<3; ++jc){
    int j = jc*256 + t;                 // this thread computes gate-row j for all 32 b
    float acc[32];
    #pragma unroll
    for (int bb=0;bb<32;bb++) acc[bb]=0.f;
    // wave-tiled W: coalesced dwordx4 per wave per k2-quad
    const float4* Wv = (const float4*)wih2 + (size_t)g*24576 + (j>>6)*2048 + (j&63);
    #pragma unroll 2
    for (int kb=0;kb<32;kb++){
      union{float4 f; h2_t h[4];} w4;
      w4.f = Wv[kb*64];
      #pragma unroll
      for (int kc=0;kc<4;kc++){
        h2_t w = w4.h[kc];
        int k2 = kb*4 + kc;
        #pragma unroll
        for (int bb=0;bb<32;bb++) acc[bb] = fdot2(x2[bb*132+k2], w, acc[bb]);
      }
    }
    float bvv = bih[j];
    int base = (g*2048 + l*B_SZ)*384 + (j>>1);
    #pragma unroll
    for (int bb=0;bb<32;bb++){
      float own = acc[bb] + bvv;
      float oth = __shfl_xor(own, 1, 64);   // pair rows (2m, 2m+1)
      if (!(t&1)){
        h2_t r; r.x=(_Float16)own; r.y=(_Float16)oth;
        gi2[base + bb*384] = r;
      }
    }
  }
}

// ============ sequential scan: encoder -> latent -> decoder. one block per b ============
struct ScanArgs {
  const float* bhh[4];
  const float* b_mean; const float* b_logv; const float* b_l2h;
  const float* enc_init; const float* eps;
};

__global__ __launch_bounds__(768) void k_scan(const int* __restrict__ edges, ScanArgs sa,
                                              const h2_t* __restrict__ wsh,
                                              h2_t* __restrict__ outs2,
                                              float* __restrict__ out){
  int b = blockIdx.x, t = threadIdx.x;
  int i = t & 255, gate = t >> 8;       // thread owns Whh row t of the selected GRU
  int lane = t & 63, rb = t >> 6;
  __shared__ float h_lds[H_SZ];
  __shared__ __align__(16) h2_t hs2[H2];
  __shared__ float g_lds[512];          // z,n pre-activations from threads 256..767
  __shared__ float s_bhh[4*G3H];        // 12 KB: all 4 bhh vectors
  __shared__ int s_edge[L_STEPS];
  const _Float16* gi_all = (const _Float16*)(wsh + GI2_OFF);

  if (t < H_SZ) h_lds[t] = sa.enc_init[b*H_SZ + t];
  if (t < L_STEPS) s_edge[t] = edges[t*B_SZ + b];
  #pragma unroll
  for (int m=0;m<4;m++) s_bhh[m*G3H + t] = sa.bhh[m][t];
  __syncthreads();
  if (t < H2){ h2_t r; r.x=(_Float16)h_lds[2*t]; r.y=(_Float16)h_lds[2*t+1]; hs2[t]=r; }
  __syncthreads();

  const float4* hsv = (const float4*)hs2;

  for (int ph=0; ph<2; ++ph){
    for (int l=0; l<L_STEPS; ++l){
      int e = s_edge[l];
      int gsel = (ph ? 2 : 0) + (e ? 0 : 1);   // edge!=0 -> child params
      // prefetch input-side gates + bias (independent of this step's dots)
      float gi0=0.f, gi1=0.f, gi2v=0.f;
      if (t < H_SZ){
        const _Float16* gr = gi_all + (size_t)(gsel*2048 + l*B_SZ + b)*G3H;
        gi0  = (float)gr[i];
        gi1  = (float)gr[256+i];
        gi2v = (float)gr[512+i];
      }
      float bv = s_bhh[gsel*G3H + t];
      // wave-tiled Whh: one coalesced dwordx4 per wave per k2-quad
      const float4* Wv = (const float4*)wsh + (size_t)gsel*24576 + rb*2048 + lane;
      float a0=0.f,a1=0.f,a2=0.f,a3=0.f;
      #pragma unroll 8
      for (int kb=0;kb<32;kb++){
        union{float4 f; h2_t h[4];} w, x;
        w.f = Wv[kb*64];
        x.f = hsv[kb];                  // LDS broadcast
        a0 = fdot2(x.h[0], w.h[0], a0);
        a1 = fdot2(x.h[1], w.h[1], a1);
        a2 = fdot2(x.h[2], w.h[2], a2);
        a3 = fdot2(x.h[3], w.h[3], a3);
      }
      float acc = (a0+a1)+(a2+a3) + bv;
      if (gate) g_lds[(gate-1)*256 + i] = acc;
      __syncthreads();                  // g_lds ready; all hs2 reads of this step done
      if (t < H_SZ){
        float r = sigm(gi0 + acc);                 // ir+hr (own dot = r-row)
        float z = sigm(gi1 + g_lds[i]);            // iz+hz
        float n = tanhf(gi2v + r*g_lds[256+i]);    // inn + r*(hn+bhh_n)
        float hn = (1.f - z)*n + z*h_lds[i];
        h_lds[i] = hn;
        float ho = __shfl_xor(hn, 1, 64);          // pair (2m,2m+1)
        if (!(i & 1)){
          h2_t pk; pk.x=(_Float16)hn; pk.y=(_Float16)ho;
          hs2[i>>1] = pk;
          if (ph) outs2[(l*B_SZ + b)*H2 + (i>>1)] = pk;
        }
      }
      __syncthreads();                  // hs2 ready for next step
    }

    if (ph == 0){
      // latent: mean/logv/z/h0 — per-b local
      if (t < H_SZ){
        const float4* WmV = (const float4*)(wsh + WM2_OFF)  + (t>>6)*2048 + (t&63);
        const float4* WlV = (const float4*)(wsh + WLV2_OFF) + (t>>6)*2048 + (t&63);
        float m0=0.f,m1=0.f,m2=0.f,m3=0.f, l0=0.f,l1=0.f,l2=0.f,l3=0.f;
        #pragma unroll 8
        for (int kb=0;kb<32;kb++){
          union{float4 f; h2_t h[4];} wm, wl, x;
          x.f  = hsv[kb];
          wm.f = WmV[kb*64];
          wl.f = WlV[kb*64];
          m0=fdot2(x.h[0],wm.h[0],m0); m1=fdot2(x.h[1],wm.h[1],m1);
          m2=fdot2(x.h[2],wm.h[2],m2); m3=fdot2(x.h[3],wm.h[3],m3);
          l0=fdot2(x.h[0],wl.h[0],l0); l1=fdot2(x.h[1],wl.h[1],l1);
          l2=fdot2(x.h[2],wl.h[2],l2); l3=fdot2(x.h[3],wl.h[3],l3);
        }
        float am = (m0+m1)+(m2+m3) + sa.b_mean[t];
        float al = (l0+l1)+(l2+l3) + sa.b_logv[t];
        float zv = sa.eps[b*Z_SZ + t] * __expf(0.5f*al) + am;
        out[OUT_MEAN_OFF + b*Z_SZ + t] = am;
        out[OUT_LOGV_OFF + b*Z_SZ + t] = al;
        out[OUT_Z_OFF    + b*Z_SZ + t] = zv;
        h_lds[t] = zv;
      }
      __syncthreads();
      if (t < H2){ h2_t r; r.x=(_Float16)h_lds[2*t]; r.y=(_Float16)h_lds[2*t+1]; hs2[t]=r; }
      __syncthreads();
      float h0v = 0.f;
      if (t < H_SZ){
        const float4* WzV = (const float4*)(wsh + WL2H2_OFF) + (t>>6)*2048 + (t&63);
        float z0=0.f,z1=0.f,z2=0.f,z3=0.f;
        #pragma unroll 8
        for (int kb=0;kb<32;kb++){
          union{float4 f; h2_t h[4];} w, x;
          x.f = hsv[kb];
          w.f = WzV[kb*64];
          z0=fdot2(x.h[0],w.h[0],z0); z1=fdot2(x.h[1],w.h[1],z1);
          z2=fdot2(x.h[2],w.h[2],z2); z3=fdot2(x.h[3],w.h[3],z3);
        }
        h0v = (z0+z1)+(z2+z3) + sa.b_l2h[t];
      }
      __syncthreads();                  // all hs2 reads of h0-dot done
      if (t < H_SZ) h_lds[t] = h0v;
      __syncthreads();
      if (t < H2){ h2_t r; r.x=(_Float16)h_lds[2*t]; r.y=(_Float16)h_lds[2*t+1]; hs2[t]=r; }
      __syncthreads();
    }
  }
}

// ============ MFMA GEMM: logits = outs @ W_voc^T + b_voc ============
// M=2048, N=32000, K=256. Block: 256 thr (4 waves), tile 64M x 128N, BK=64.
// Wave (wm=w&1, wn=w>>1): 32M x 64N via 2x4 frags of mfma_f32_16x16x32_f16.
// LDS tiles XOR-swizzled: 16B-slot s of row r stored at s^(r&7)  (T2, kills
// the 16-way conflict of 128B-row column reads).
__global__ __launch_bounds__(256) void k_gemm2(const h2_t* __restrict__ outs2,
                                               const _Float16* __restrict__ wv16,
                                               const float* __restrict__ bvoc,
                                               float* __restrict__ outf){
  int t = threadIdx.x;
  int lane = t & 63, w = t >> 6;
  int wm = w & 1, wn = w >> 1;
  int Mb = blockIdx.x * 64, Nb = blockIdx.y * 128;
  int lr = lane & 15, lq = lane >> 4;          // frag row/col, k-group

  __shared__ __align__(16) _Float16 As[64*64];     // 8 KB  [row][k] swizzled
  __shared__ __align__(16) _Float16 Bs[128*64];    // 16 KB [v][k]  swizzled

  f32x4 acc[2][4];
  #pragma unroll
  for (int mi=0;mi<2;mi++)
    #pragma unroll
    for (int nj=0;nj<4;nj++) acc[mi][nj] = (f32x4){0.f,0.f,0.f,0.f};

  for (int kc=0; kc<4; ++kc){
    // ---- stage A: 512 16B-chunks, 2/thread ----
    #pragma unroll
    for (int q=0;q<2;q++){
      int ch = q*256 + t;
      int row = ch >> 3, kb = ch & 7;
      float4 d = ((const float4*)(outs2 + (size_t)(Mb + row)*H2 + kc*32))[kb];
      ((float4*)As)[row*8 + (kb ^ (row & 7))] = d;
    }
    // ---- stage B: 1024 16B-chunks, 4/thread ----
    #pragma unroll
    for (int q=0;q<4;q++){
      int ch = q*256 + t;
      int row = ch >> 3, kb = ch & 7;
      float4 d = ((const float4*)(wv16 + (size_t)(Nb + row)*H_SZ + kc*64))[kb];
      ((float4*)Bs)[row*8 + (kb ^ (row & 7))] = d;
    }
    __syncthreads();
    // ---- fragments + MFMA ----
    union{float4 f; f16x8 h;} af[2][2], bf[4][2];
    #pragma unroll
    for (int mi=0;mi<2;mi++)
      #pragma unroll
      for (int kk=0;kk<2;kk++){
        int row = wm*32 + mi*16 + lr;
        int ks = kk*4 + lq;
        af[mi][kk].f = ((const float4*)As)[row*8 + (ks ^ (row & 7))];
      }
    #pragma unroll
    for (int nj=0;nj<4;nj++)
      #pragma unroll
      for (int kk=0;kk<2;kk++){
        int row = wn*64 + nj*16 + lr;
        int ks = kk*4 + lq;
        bf[nj][kk].f = ((const float4*)Bs)[row*8 + (ks ^ (row & 7))];
      }
    #pragma unroll
    for (int kk=0;kk<2;kk++)
      #pragma unroll
      for (int mi=0;mi<2;mi++)
        #pragma unroll
        for (int nj=0;nj<4;nj++)
          acc[mi][nj] = __builtin_amdgcn_mfma_f32_16x16x32_f16(
                          af[mi][kk].h, bf[nj][kk].h, acc[mi][nj], 0, 0, 0);
    __syncthreads();
  }

  // ---- epilogue: C/D layout col=lane&15, row=(lane>>4)*4+reg ----
  #pragma unroll
  for (int nj=0;nj<4;nj++){
    int col = Nb + wn*64 + nj*16 + lr;
    float bias = bvoc[col];
    #pragma unroll
    for (int mi=0;mi<2;mi++){
      int r0 = Mb + wm*32 + mi*16 + lq*4;
      #pragma unroll
      for (int rg=0;rg<4;rg++)
        outf[(size_t)(r0 + rg)*V_SZ + col] = acc[mi][nj][rg] + bias;
    }
  }
}

// ============ fallback fdot2 GEMM (used only if ws too small for W16) ============
__global__ __launch_bounds__(512) void k_gemm(const h2_t* __restrict__ outs2,
                                              const float* __restrict__ wv,
                                              const float* __restrict__ bvoc,
                                              float* __restrict__ outf){
  int t = threadIdx.x;
  int vq = t & 31, rq = t >> 5;          // rq 0..15
  int Nb = blockIdx.x * 256, Mb = blockIdx.y * 128;
  __shared__ __align__(16) h2_t A[16*128];    // [k2][r]
  __shared__ __align__(16) h2_t Bss[16*256];  // [k2][v]
  float acc[8][8];
  #pragma unroll
  for (int a=0;a<8;a++){
    #pragma unroll
    for (int c=0;c<8;c++) acc[a][c]=0.f;
  }

  for (int kc=0;kc<8;kc++){
    {
      int r = t >> 2, q = t & 3;
      union{float4 f; h2_t h[4];} u;
      u.f = ((const float4*)(outs2 + (Mb + r)*H2 + kc*16))[q];
      #pragma unroll
      for (int uu=0; uu<4; ++uu) A[(q*4+uu)*128 + r] = u.h[uu];
    }
    {
      int v = t >> 1, q = t & 1;
      const float* wrow = wv + (size_t)(Nb + v)*H_SZ + kc*32 + q*16;
      #pragma unroll
      for (int p=0;p<4;p++){
        float4 f = ((const float4*)wrow)[p];
        h2_t h0; h0.x=(_Float16)f.x; h0.y=(_Float16)f.y;
        h2_t h1; h1.x=(_Float16)f.z; h1.y=(_Float16)f.w;
        Bss[(q*8+p*2  )*256 + v] = h0;
        Bss[(q*8+p*2+1)*256 + v] = h1;
      }
    }
    __syncthreads();
    #pragma unroll 2
    for (int k2=0;k2<16;k2++){
      union{float4 f; h2_t h[4];} a0, a1, b0, b1;
      a0.f = *(const float4*)(A  + k2*128 + rq*8);
      a1.f = *(const float4*)(A  + k2*128 + rq*8 + 4);
      b0.f = *(const float4*)(Bss + k2*256 + vq*4);
      b1.f = *(const float4*)(Bss + k2*256 + vq*4 + 128);
      #pragma unroll
      for (int ii=0;ii<8;ii++){
        h2_t av = (ii<4)? a0.h[ii] : a1.h[ii-4];
        #pragma unroll
        for (int jj=0;jj<8;jj++){
          h2_t bv = (jj<4)? b0.h[jj] : b1.h[jj-4];
          acc[ii][jj] = fdot2(av, bv, acc[ii][jj]);
        }
      }
    }
    __syncthreads();
  }

  float bias0[4], bias1[4];
  #pragma unroll
  for (int jj=0;jj<4;jj++){
    bias0[jj] = bvoc[Nb + 4*vq + jj];
    bias1[jj] = bvoc[Nb + 128 + 4*vq + jj];
  }
  #pragma unroll
  for (int ii=0;ii<8;ii++){
    size_t base = (size_t)(Mb + rq*8 + ii)*(size_t)V_SZ + (size_t)Nb;
    float4 o0, o1;
    o0.x = acc[ii][0]+bias0[0]; o0.y = acc[ii][1]+bias0[1];
    o0.z = acc[ii][2]+bias0[2]; o0.w = acc[ii][3]+bias0[3];
    o1.x = acc[ii][4]+bias1[0]; o1.y = acc[ii][5]+bias1[1];
    o1.z = acc[ii][6]+bias1[2]; o1.w = acc[ii][7]+bias1[3];
    *(float4*)(outf + base + 4*vq)       = o0;
    *(float4*)(outf + base + 128 + 4*vq) = o1;
  }
}

// ============ per-row log_softmax in-place over fp32 logits (register-resident row) ============
__global__ __launch_bounds__(256) void k_softmax(float* __restrict__ outf){
  int rrow = blockIdx.x, t = threadIdx.x;
  float4* row = (float4*)(outf + (size_t)rrow * V_SZ);   // 8000 float4
  float4 v[32];
  #pragma unroll
  for (int i=0;i<31;i++) v[i] = row[i*256 + t];
  if (t < 64) v[31] = row[7936 + t];
  else { v[31].x = -1e30f; v[31].y = -1e30f; v[31].z = -1e30f; v[31].w = -1e30f; }

  float m = -1e30f;
  #pragma unroll
  for (int i=0;i<32;i++) m = fmaxf(m, fmaxf(fmaxf(v[i].x, v[i].y), fmaxf(v[i].z, v[i].w)));

  __shared__ float sred[4];
  __shared__ float sbc;
  int wid = t >> 6, lane = t & 63;
  #pragma unroll
  for (int o=32;o;o>>=1) m = fmaxf(m, __shfl_xor(m, o, 64));
  if (lane==0) sred[wid] = m;
  __syncthreads();
  if (t==0) sbc = fmaxf(fmaxf(sred[0],sred[1]), fmaxf(sred[2],sred[3]));
  __syncthreads();
  m = sbc;
  __syncthreads();

  float s = 0.f;
  #pragma unroll
  for (int i=0;i<32;i++){
    s += __expf(v[i].x - m) + __expf(v[i].y - m) + __expf(v[i].z - m) + __expf(v[i].w - m);
  }
  #pragma unroll
  for (int o=32;o;o>>=1) s += __shfl_xor(s, o, 64);
  if (lane==0) sred[wid] = s;
  __syncthreads();
  if (t==0) sbc = sred[0]+sred[1]+sred[2]+sred[3];
  __syncthreads();
  float lse = m + logf(sbc);

  #pragma unroll
  for (int i=0;i<31;i++){
    v[i].x -= lse; v[i].y -= lse; v[i].z -= lse; v[i].w -= lse;
    row[i*256 + t] = v[i];
  }
  if (t < 64){
    v[31].x -= lse; v[31].y -= lse; v[31].z -= lse; v[31].w -= lse;
    row[7936 + t] = v[31];
  }
}

// ============================================================================
extern "C" void kernel_launch(void* const* d_in, const int* in_sizes, int n_in,
                              void* d_out, int out_size, void* d_ws, size_t ws_size,
                              hipStream_t stream){
  const int* nodes = (const int*)d_in[0];
  const int* edges = (const int*)d_in[1];
  h2_t* wsh = (h2_t*)d_ws;
  float* outf = (float*)d_out;
  bool mfma_path = (ws_size >= WS_NEEDED);

  // ---- pack recurrent/latent weights fp32 -> f16, wave-tiled ----
  PackTArgs pt;
  const int srcidx[11] = {6,10,14,18, 5,9,13,17, 21,23,25};
  for (int k=0;k<11;k++){
    pt.src[k] = (const float2*)d_in[srcidx[k]];
    pt.n_h2[k] = (k < 8) ? 98304 : 32768;
  }
  for (int k=0;k<4;k++) pt.dstoff[k]   = WHH2_OFF + k*98304;
  for (int k=0;k<4;k++) pt.dstoff[4+k] = WIH2_OFF + k*98304;
  pt.dstoff[8] = WM2_OFF; pt.dstoff[9] = WLV2_OFF; pt.dstoff[10] = WL2H2_OFF;
  k_packt<<<dim3(384,11), dim3(256), 0, stream>>>(pt, wsh);

  // ---- pack W_voc fp32 -> f16 row-major (for MFMA GEMM) ----
  if (mfma_path)
    k_packv<<<dim3(16000), dim3(256), 0, stream>>>((const float2*)d_in[27],
                                                   wsh + W16_OFF, 4096000);

  // ---- gi precompute (f16) ----
  GiArgs ga;
  ga.bih[0]=(const float*)d_in[7];  ga.bih[1]=(const float*)d_in[11];
  ga.bih[2]=(const float*)d_in[15]; ga.bih[3]=(const float*)d_in[19];
  k_gi<<<dim3(64,4), dim3(256), 0, stream>>>(nodes, (const float*)d_in[4], wsh + WIH2_OFF, ga, wsh + GI2_OFF);

  // ---- recurrent scan (enc -> latent -> dec), one block per b ----
  ScanArgs sa;
  sa.bhh[0]=(const float*)d_in[8];  sa.bhh[1]=(const float*)d_in[12];
  sa.bhh[2]=(const float*)d_in[16]; sa.bhh[3]=(const float*)d_in[20];
  sa.b_mean=(const float*)d_in[22]; sa.b_logv=(const float*)d_in[24]; sa.b_l2h=(const float*)d_in[26];
  sa.enc_init=(const float*)d_in[2]; sa.eps=(const float*)d_in[3];
  k_scan<<<dim3(32), dim3(768), 0, stream>>>(edges, sa, wsh, wsh + OUTS2_OFF, outf);

  // ---- vocab projection (fp32 logits into d_out) ----
  if (mfma_path)
    k_gemm2<<<dim3(32,250), dim3(256), 0, stream>>>(wsh + OUTS2_OFF,
                                                    (const _Float16*)(wsh + W16_OFF),
                                                    (const float*)d_in[28], outf);
  else
    k_gemm<<<dim3(125,16), dim3(512), 0, stream>>>(wsh + OUTS2_OFF, (const float*)d_in[27],
                                                   (const float*)d_in[28], outf);

  // ---- log_softmax in place ----
  k_softmax<<<dim3(2048), dim3(256), 0, stream>>>(outf);
}